// Round 1
// baseline (1046.045 us; speedup 1.0000x reference)
//
#include <hip/hip_runtime.h>
#include <hip/hip_bf16.h>
#include <cstdint>

#define S_ 2048
#define M_ 512
#define L_ 2560
#define D_ 1024
#define F_ 4096
#define H_ 16
#define DH_ 64
#define W_ 256
#define NR_ 513
#define NRP_ 640

typedef unsigned int uint32;
typedef __attribute__((ext_vector_type(8))) short bf16x8;
typedef __attribute__((ext_vector_type(4))) float f32x4;

__device__ __forceinline__ ushort f2bf(float f) {
  uint32 u = __builtin_bit_cast(uint32, f);
  u += 0x7FFFu + ((u >> 16) & 1u);
  return (ushort)(u >> 16);
}
__device__ __forceinline__ float bf2f(ushort s) {
  uint32 u = ((uint32)s) << 16;
  return __builtin_bit_cast(float, u);
}
__device__ __forceinline__ float bflo(uint32 w) { return __builtin_bit_cast(float, w << 16); }
__device__ __forceinline__ float bfhi(uint32 w) { return __builtin_bit_cast(float, w & 0xFFFF0000u); }

__device__ __forceinline__ ushort4 pack4(float4 vf) {
  ushort4 r;
  r.x = f2bf(vf.x); r.y = f2bf(vf.y); r.z = f2bf(vf.z); r.w = f2bf(vf.w);
  return r;
}

__device__ __forceinline__ float gelu_tanh(float x) {
  float t = 0.7978845608028654f * x * (1.f + 0.044715f * x * x);
  float e = __expf(2.f * t);
  float th = 1.f - 2.f / (e + 1.f);
  return 0.5f * x * (1.f + th);
}

// ---------------- transpose fp32 [R][C] -> bf16 [C][R] ----------------
__global__ __launch_bounds__(256)
void transpose_f32_to_bf16(const float* __restrict__ in, ushort* __restrict__ out,
                           int R, int C) {
  __shared__ float tile[32][33];
  const int c0 = blockIdx.x * 32, r0 = blockIdx.y * 32;
  const int tx = threadIdx.x, ty = threadIdx.y;  // block (32,8)
#pragma unroll
  for (int i = 0; i < 4; i++)
    tile[ty + i * 8][tx] = in[(size_t)(r0 + ty + i * 8) * C + c0 + tx];
  __syncthreads();
#pragma unroll
  for (int i = 0; i < 4; i++)
    out[(size_t)(c0 + ty + i * 8) * R + r0 + tx] = f2bf(tile[tx][ty + i * 8]);
}

// ---------------- pack x and kv=concat(mem,x) to bf16 ----------------
__global__ __launch_bounds__(256)
void cvt_x_kv(const float* __restrict__ x, const float* __restrict__ mem,
              ushort* __restrict__ xb, ushort* __restrict__ kvb) {
  int idx = blockIdx.x * 256 + threadIdx.x;
  const int nxq = S_ * D_ / 4;
  const int nkq = L_ * D_ / 4;
  if (idx < nxq) {
    ((ushort4*)xb)[idx] = pack4(((const float4*)x)[idx]);
  } else {
    int k = idx - nxq;
    if (k < nkq) {
      int l = k >> 8;     // D_/4 = 256 quads per row
      int c = k & 255;
      const float4* src = (l < M_) ? (const float4*)(mem + (size_t)l * D_)
                                   : (const float4*)(x + (size_t)(l - M_) * D_);
      ((ushort4*)kvb)[k] = pack4(src[c]);
    }
  }
}

// ---------------- sinusoid rel-pos embedding rows d in [-W,W] ----------------
__global__ __launch_bounds__(256)
void sinusoid_kernel(ushort* __restrict__ remb) {
  int idx = blockIdx.x * 256 + threadIdx.x;   // r*512 + f
  int r = idx >> 9, f = idx & 511;
  if (r >= NRP_) return;
  if (r < NR_) {
    float invf = expf(-(float)f * (9.210340371976184f / 512.0f)); // 10000^(-f/512)
    float ang = (float)(r - W_) * invf;
    remb[(size_t)r * D_ + f] = f2bf(sinf(ang));
    remb[(size_t)r * D_ + 512 + f] = f2bf(cosf(ang));
  } else {
    remb[(size_t)r * D_ + f] = 0;
    remb[(size_t)r * D_ + 512 + f] = 0;
  }
}

// ---------------- MFMA GEMM: C[M,N] = A[M,K](bf16) x BT[N,K]^T(bf16) ----------------
// EPI: 0 = bf16 out, 1 = f32 out, 2 = bf16(gelu(c+bias)), 3 = f32(c+bias)
template <int EPI>
__global__ __launch_bounds__(256)
void gemm_bt(const ushort* __restrict__ A, const ushort* __restrict__ BT,
             void* __restrict__ Cout, const float* __restrict__ bias,
             int Msz, int Nsz, int Ksz) {
  __shared__ __align__(16) ushort As[4][128][8];  // [kgroup][row ^ (2*kg)][8 bf16]
  __shared__ __align__(16) ushort Bs[4][128][8];
  const int tid = threadIdx.x;
  const int wave = tid >> 6, lane = tid & 63;
  const int wr = wave >> 1, wc = wave & 1;
  const int brow = blockIdx.y * 128, bcol = blockIdx.x * 128;

  f32x4 acc[4][4] = {};

  const int srow = tid >> 2;   // 0..63
  const int skg = tid & 3;
  const int wsw = skg * 2;

  const ushort* Ap0 = A + (size_t)(brow + srow) * Ksz + skg * 8;
  const ushort* Ap1 = A + (size_t)(brow + srow + 64) * Ksz + skg * 8;
  const ushort* Bp0 = BT + (size_t)(bcol + srow) * Ksz + skg * 8;
  const ushort* Bp1 = BT + (size_t)(bcol + srow + 64) * Ksz + skg * 8;

  uint4 a0 = *(const uint4*)Ap0;
  uint4 a1 = *(const uint4*)Ap1;
  uint4 b0 = *(const uint4*)Bp0;
  uint4 b1 = *(const uint4*)Bp1;

  const int kg = lane >> 4;
  const int rsw = kg * 2;
  const int fr = lane & 15;

  for (int k0 = 0; k0 < Ksz; k0 += 32) {
    __syncthreads();
    *(uint4*)&As[skg][srow ^ wsw][0] = a0;
    *(uint4*)&As[skg][(srow + 64) ^ wsw][0] = a1;
    *(uint4*)&Bs[skg][srow ^ wsw][0] = b0;
    *(uint4*)&Bs[skg][(srow + 64) ^ wsw][0] = b1;
    __syncthreads();
    if (k0 + 32 < Ksz) {
      a0 = *(const uint4*)(Ap0 + k0 + 32);
      a1 = *(const uint4*)(Ap1 + k0 + 32);
      b0 = *(const uint4*)(Bp0 + k0 + 32);
      b1 = *(const uint4*)(Bp1 + k0 + 32);
    }
    bf16x8 af[4], bfv[4];
#pragma unroll
    for (int m = 0; m < 4; m++)
      af[m] = *(const bf16x8*)&As[kg][(wr * 64 + m * 16 + fr) ^ rsw][0];
#pragma unroll
    for (int n = 0; n < 4; n++)
      bfv[n] = *(const bf16x8*)&Bs[kg][(wc * 64 + n * 16 + fr) ^ rsw][0];
#pragma unroll
    for (int m = 0; m < 4; m++) {
#pragma unroll
      for (int n = 0; n < 4; n++) {
        acc[m][n] = __builtin_amdgcn_mfma_f32_16x16x32_bf16(af[m], bfv[n], acc[m][n], 0, 0, 0);
      }
    }
  }

  const int r4 = (lane >> 4) * 4;
#pragma unroll
  for (int m = 0; m < 4; m++) {
#pragma unroll
    for (int n = 0; n < 4; n++) {
      const int col = bcol + wc * 64 + n * 16 + fr;
#pragma unroll
      for (int r = 0; r < 4; r++) {
        const int row = brow + wr * 64 + m * 16 + r4 + r;
        float val = acc[m][n][r];
        size_t o = (size_t)row * Nsz + col;
        if constexpr (EPI == 0) ((ushort*)Cout)[o] = f2bf(val);
        else if constexpr (EPI == 1) ((float*)Cout)[o] = val;
        else if constexpr (EPI == 2) ((ushort*)Cout)[o] = f2bf(gelu_tanh(val + bias[col]));
        else ((float*)Cout)[o] = val + bias[col];
      }
    }
  }
}

// ---------------- banded attention (vector-ALU v1) ----------------
// Rb row r corresponds to dist d = r - W; key slot s (j = jlo+s) -> dist W-s -> row 2W-s.
__global__ __launch_bounds__(256)
void attn_kernel(const ushort* __restrict__ qb, const ushort* __restrict__ kb,
                 const ushort* __restrict__ vb, const ushort* __restrict__ Rb,
                 const float* __restrict__ ubias, const float* __restrict__ vbias,
                 ushort* __restrict__ attb) {
  const int h = blockIdx.y;
  const int i0 = blockIdx.x * 16;
  const int tid = threadIdx.x, wave = tid >> 6, lane = tid & 63;
  __shared__ __align__(16) float squ[16][64];
  __shared__ __align__(16) float sqv[16][64];
  __shared__ float p[16][516];

#pragma unroll
  for (int e = 0; e < 4; e++) {
    int idx = tid + e * 256;
    int ql = idx >> 6, d = idx & 63;
    float qf = bf2f(qb[(size_t)(i0 + ql) * D_ + h * DH_ + d]);
    squ[ql][d] = qf + ubias[h * DH_ + d];
    sqv[ql][d] = qf + vbias[h * DH_ + d];
  }
  __syncthreads();

  for (int s4 = 0; s4 < 4; s4++) {
    const int ql = wave * 4 + s4;
    const int qi = i0 + ql;
    const int jlo = M_ + qi - W_;
    const int jhi = (M_ + qi + W_ < L_ - 1) ? (M_ + qi + W_) : (L_ - 1);
    const int cnt = jhi - jlo + 1;

    float mx = -1e30f;
    for (int s = lane; s < cnt; s += 64) {
      const int j = jlo + s;
      const uint4* kr = (const uint4*)(kb + (size_t)j * D_ + h * DH_);
      const uint4* rr = (const uint4*)(Rb + (size_t)(2 * W_ - s) * D_ + h * DH_);
      const float4* quv = (const float4*)(&squ[ql][0]);
      const float4* qvv = (const float4*)(&sqv[ql][0]);
      float ac = 0.f, bd = 0.f;
#pragma unroll
      for (int e = 0; e < 8; e++) {
        uint4 kk = kr[e];
        uint4 rw = rr[e];
        float4 qa = quv[2 * e], qc = quv[2 * e + 1];
        float4 pa = qvv[2 * e], pc = qvv[2 * e + 1];
        ac += qa.x * bflo(kk.x) + qa.y * bfhi(kk.x) + qa.z * bflo(kk.y) + qa.w * bfhi(kk.y)
            + qc.x * bflo(kk.z) + qc.y * bfhi(kk.z) + qc.z * bflo(kk.w) + qc.w * bfhi(kk.w);
        bd += pa.x * bflo(rw.x) + pa.y * bfhi(rw.x) + pa.z * bflo(rw.y) + pa.w * bfhi(rw.y)
            + pc.x * bflo(rw.z) + pc.y * bfhi(rw.z) + pc.z * bflo(rw.w) + pc.w * bfhi(rw.w);
      }
      float sc = (ac + bd) * 0.125f;
      p[ql][s] = sc;
      mx = fmaxf(mx, sc);
    }
#pragma unroll
    for (int off = 32; off; off >>= 1) mx = fmaxf(mx, __shfl_xor(mx, off));

    float sm = 0.f;
    for (int s = lane; s < cnt; s += 64) {
      float e = __expf(p[ql][s] - mx);
      p[ql][s] = e;
      sm += e;
    }
#pragma unroll
    for (int off = 32; off; off >>= 1) sm += __shfl_xor(sm, off);
    const float inv = 1.f / sm;

    float o = 0.f;
    const ushort* vcol = vb + h * DH_ + lane;
#pragma unroll 4
    for (int s = 0; s < cnt; s++) {
      o += p[ql][s] * bf2f(vcol[(size_t)(jlo + s) * D_]);
    }
    attb[(size_t)qi * D_ + h * DH_ + lane] = f2bf(o * inv);
  }
}

// ---------------- residual + LayerNorm ----------------
__global__ __launch_bounds__(256)
void ln_kernel(const float* __restrict__ a, const float* __restrict__ b,
               const float* __restrict__ gamma, const float* __restrict__ beta,
               float* __restrict__ outf, ushort* __restrict__ outb) {
  const int row = blockIdx.x;
  const int tid = threadIdx.x;
  const int wave = tid >> 6, lane = tid & 63;
  float4 va = ((const float4*)(a + (size_t)row * D_))[tid];
  float4 vb4 = ((const float4*)(b + (size_t)row * D_))[tid];
  float4 xv;
  xv.x = va.x + vb4.x; xv.y = va.y + vb4.y; xv.z = va.z + vb4.z; xv.w = va.w + vb4.w;
  float s = xv.x + xv.y + xv.z + xv.w;
  float q = xv.x * xv.x + xv.y * xv.y + xv.z * xv.z + xv.w * xv.w;
#pragma unroll
  for (int off = 32; off; off >>= 1) { s += __shfl_xor(s, off); q += __shfl_xor(q, off); }
  __shared__ float red[8];
  if (lane == 0) { red[wave * 2] = s; red[wave * 2 + 1] = q; }
  __syncthreads();
  float ts = red[0] + red[2] + red[4] + red[6];
  float tq = red[1] + red[3] + red[5] + red[7];
  float mu = ts * (1.f / D_);
  float var = tq * (1.f / D_) - mu * mu;
  float rs = rsqrtf(var + 1e-5f);
  float4 g4 = ((const float4*)gamma)[tid];
  float4 be4 = ((const float4*)beta)[tid];
  float4 y;
  y.x = (xv.x - mu) * rs * g4.x + be4.x;
  y.y = (xv.y - mu) * rs * g4.y + be4.y;
  y.z = (xv.z - mu) * rs * g4.z + be4.z;
  y.w = (xv.w - mu) * rs * g4.w + be4.w;
  ((float4*)(outf + (size_t)row * D_))[tid] = y;
  if (outb) ((ushort4*)(outb + (size_t)row * D_))[tid] = pack4(y);
}

extern "C" void kernel_launch(void* const* d_in, const int* in_sizes, int n_in,
                              void* d_out, int out_size, void* d_ws, size_t ws_size,
                              hipStream_t stream) {
  const float* x    = (const float*)d_in[0];
  const float* mem  = (const float*)d_in[1];
  const float* Wq   = (const float*)d_in[2];
  const float* Wk   = (const float*)d_in[3];
  const float* Wv   = (const float*)d_in[4];
  const float* Wo   = (const float*)d_in[5];
  const float* Wr   = (const float*)d_in[6];
  const float* u    = (const float*)d_in[7];
  const float* v    = (const float*)d_in[8];
  const float* ln1g = (const float*)d_in[9];
  const float* ln1b = (const float*)d_in[10];
  const float* W1   = (const float*)d_in[11];
  const float* b1   = (const float*)d_in[12];
  const float* W2   = (const float*)d_in[13];
  const float* b2   = (const float*)d_in[14];
  const float* ln2g = (const float*)d_in[15];
  const float* ln2b = (const float*)d_in[16];
  float* out = (float*)d_out;

  char* ws = (char*)d_ws;
  size_t off = 0;
  auto take = [&](size_t n) { char* p = ws + off; off += (n + 255) & ~(size_t)255; return p; };

  ushort* WqT = (ushort*)take(2097152);
  ushort* WkT = (ushort*)take(2097152);
  ushort* WvT = (ushort*)take(2097152);
  ushort* WoT = (ushort*)take(2097152);
  ushort* WrT = (ushort*)take(2097152);
  ushort* W1T = (ushort*)take(8388608);   // [4096][1024]
  ushort* W2T = (ushort*)take(8388608);   // [1024][4096]

  char* regA = take(10747904);            // xb + kvb + remb; later reused for f
  ushort* xb   = (ushort*)regA;                       // 4,194,304 B
  ushort* kvb  = (ushort*)(regA + 4194304);           // 5,242,880 B
  ushort* remb = (ushort*)(regA + 4194304 + 5242880); // 1,310,720 B
  float*  fbuf = (float*)regA;                        // 8,388,608 B (overlay)

  char* regB = take(20185088);            // qb,kb,vb,Rb,attb; later reused for g
  ushort* qb   = (ushort*)regB;
  ushort* kb   = (ushort*)(regB + 4194304);
  ushort* vb   = (ushort*)(regB + 9437184);
  ushort* Rb   = (ushort*)(regB + 14680064);
  ushort* attb = (ushort*)(regB + 15990784);
  ushort* g    = (ushort*)regB;                       // 16,777,216 B (overlay)

  float*  o2 = (float*)take(8388608);
  float*  h  = (float*)take(8388608);
  ushort* hb = (ushort*)take(4194304);

  dim3 tb(32, 8);
  transpose_f32_to_bf16<<<dim3(32, 32), tb, 0, stream>>>(Wq, WqT, 1024, 1024);
  transpose_f32_to_bf16<<<dim3(32, 32), tb, 0, stream>>>(Wk, WkT, 1024, 1024);
  transpose_f32_to_bf16<<<dim3(32, 32), tb, 0, stream>>>(Wv, WvT, 1024, 1024);
  transpose_f32_to_bf16<<<dim3(32, 32), tb, 0, stream>>>(Wo, WoT, 1024, 1024);
  transpose_f32_to_bf16<<<dim3(32, 32), tb, 0, stream>>>(Wr, WrT, 1024, 1024);
  transpose_f32_to_bf16<<<dim3(128, 32), tb, 0, stream>>>(W1, W1T, 1024, 4096);
  transpose_f32_to_bf16<<<dim3(32, 128), tb, 0, stream>>>(W2, W2T, 4096, 1024);

  cvt_x_kv<<<4608, 256, 0, stream>>>(x, mem, xb, kvb);
  sinusoid_kernel<<<1280, 256, 0, stream>>>(remb);

  gemm_bt<0><<<dim3(8, 16), 256, 0, stream>>>(xb,   WqT, qb, nullptr, 2048, 1024, 1024);
  gemm_bt<0><<<dim3(8, 20), 256, 0, stream>>>(kvb,  WkT, kb, nullptr, 2560, 1024, 1024);
  gemm_bt<0><<<dim3(8, 20), 256, 0, stream>>>(kvb,  WvT, vb, nullptr, 2560, 1024, 1024);
  gemm_bt<0><<<dim3(8, 5),  256, 0, stream>>>(remb, WrT, Rb, nullptr, 640, 1024, 1024);

  attn_kernel<<<dim3(128, 16), 256, 0, stream>>>(qb, kb, vb, Rb, u, v, attb);

  gemm_bt<1><<<dim3(8, 16), 256, 0, stream>>>(attb, WoT, o2, nullptr, 2048, 1024, 1024);
  ln_kernel<<<2048, 256, 0, stream>>>(x, o2, ln1g, ln1b, h, hb);
  gemm_bt<2><<<dim3(32, 16), 256, 0, stream>>>(hb, W1T, g, b1, 2048, 4096, 1024);
  gemm_bt<3><<<dim3(8, 16), 256, 0, stream>>>(g, W2T, fbuf, b2, 2048, 1024, 4096);
  ln_kernel<<<2048, 256, 0, stream>>>(h, fbuf, ln2g, ln2b, out, nullptr);
}

// Round 2
// 293.211 us; speedup vs baseline: 3.5676x; 3.5676x over previous
//
#include <hip/hip_runtime.h>
#include <hip/hip_bf16.h>
#include <cstdint>

#define S_ 2048
#define M_ 512
#define L_ 2560
#define D_ 1024
#define F_ 4096
#define H_ 16
#define DH_ 64
#define W_ 256
#define NR_ 513
#define NRP_ 640

typedef unsigned int uint32;
typedef __attribute__((ext_vector_type(8))) short bf16x8;
typedef __attribute__((ext_vector_type(4))) float f32x4;

__device__ __forceinline__ ushort f2bf(float f) {
  uint32 u = __builtin_bit_cast(uint32, f);
  u += 0x7FFFu + ((u >> 16) & 1u);
  return (ushort)(u >> 16);
}
__device__ __forceinline__ float bf2f(ushort s) {
  uint32 u = ((uint32)s) << 16;
  return __builtin_bit_cast(float, u);
}
__device__ __forceinline__ float bflo(uint32 w) { return __builtin_bit_cast(float, w << 16); }
__device__ __forceinline__ float bfhi(uint32 w) { return __builtin_bit_cast(float, w & 0xFFFF0000u); }

__device__ __forceinline__ ushort4 pack4(float4 vf) {
  ushort4 r;
  r.x = f2bf(vf.x); r.y = f2bf(vf.y); r.z = f2bf(vf.z); r.w = f2bf(vf.w);
  return r;
}

__device__ __forceinline__ float gelu_tanh(float x) {
  float t = 0.7978845608028654f * x * (1.f + 0.044715f * x * x);
  float e = __expf(2.f * t);
  float th = 1.f - 2.f / (e + 1.f);
  return 0.5f * x * (1.f + th);
}

// ---------------- transpose fp32 [R][C] -> bf16 [C][R] ----------------
__global__ __launch_bounds__(256)
void transpose_f32_to_bf16(const float* __restrict__ in, ushort* __restrict__ out,
                           int R, int C) {
  __shared__ float tile[32][33];
  const int c0 = blockIdx.x * 32, r0 = blockIdx.y * 32;
  const int tx = threadIdx.x, ty = threadIdx.y;  // block (32,8)
#pragma unroll
  for (int i = 0; i < 4; i++)
    tile[ty + i * 8][tx] = in[(size_t)(r0 + ty + i * 8) * C + c0 + tx];
  __syncthreads();
#pragma unroll
  for (int i = 0; i < 4; i++)
    out[(size_t)(c0 + ty + i * 8) * R + r0 + tx] = f2bf(tile[tx][ty + i * 8]);
}

// ---------------- pack x and kv=concat(mem,x) to bf16 ----------------
__global__ __launch_bounds__(256)
void cvt_x_kv(const float* __restrict__ x, const float* __restrict__ mem,
              ushort* __restrict__ xb, ushort* __restrict__ kvb) {
  int idx = blockIdx.x * 256 + threadIdx.x;
  const int nxq = S_ * D_ / 4;
  const int nkq = L_ * D_ / 4;
  if (idx < nxq) {
    ((ushort4*)xb)[idx] = pack4(((const float4*)x)[idx]);
  } else {
    int k = idx - nxq;
    if (k < nkq) {
      int l = k >> 8;     // D_/4 = 256 quads per row
      int c = k & 255;
      const float4* src = (l < M_) ? (const float4*)(mem + (size_t)l * D_)
                                   : (const float4*)(x + (size_t)(l - M_) * D_);
      ((ushort4*)kvb)[k] = pack4(src[c]);
    }
  }
}

// ---------------- sinusoid rel-pos embedding rows d in [-W,W] ----------------
__global__ __launch_bounds__(256)
void sinusoid_kernel(ushort* __restrict__ remb) {
  int idx = blockIdx.x * 256 + threadIdx.x;   // r*512 + f
  int r = idx >> 9, f = idx & 511;
  if (r >= NRP_) return;
  if (r < NR_) {
    float invf = expf(-(float)f * (9.210340371976184f / 512.0f)); // 10000^(-f/512)
    float ang = (float)(r - W_) * invf;
    remb[(size_t)r * D_ + f] = f2bf(sinf(ang));
    remb[(size_t)r * D_ + 512 + f] = f2bf(cosf(ang));
  } else {
    remb[(size_t)r * D_ + f] = 0;
    remb[(size_t)r * D_ + 512 + f] = 0;
  }
}

// ---------------- MFMA GEMM: C[M,N] = A[M,K](bf16) x BT[N,K]^T(bf16) ----------------
// EPI: 0 = bf16 out, 1 = f32 out, 2 = bf16(gelu(c+bias)), 3 = f32(c+bias),
//      4 = bf16 TRANSPOSED out (Cout[col][row], ld = Msz)
template <int EPI>
__global__ __launch_bounds__(256)
void gemm_bt(const ushort* __restrict__ A, const ushort* __restrict__ BT,
             void* __restrict__ Cout, const float* __restrict__ bias,
             int Msz, int Nsz, int Ksz) {
  __shared__ __align__(16) ushort As[4][128][8];  // [kgroup][row ^ (2*kg)][8 bf16]
  __shared__ __align__(16) ushort Bs[4][128][8];
  const int tid = threadIdx.x;
  const int wave = tid >> 6, lane = tid & 63;
  const int wr = wave >> 1, wc = wave & 1;
  const int brow = blockIdx.y * 128, bcol = blockIdx.x * 128;

  f32x4 acc[4][4] = {};

  const int srow = tid >> 2;   // 0..63
  const int skg = tid & 3;
  const int wsw = skg * 2;

  const ushort* Ap0 = A + (size_t)(brow + srow) * Ksz + skg * 8;
  const ushort* Ap1 = A + (size_t)(brow + srow + 64) * Ksz + skg * 8;
  const ushort* Bp0 = BT + (size_t)(bcol + srow) * Ksz + skg * 8;
  const ushort* Bp1 = BT + (size_t)(bcol + srow + 64) * Ksz + skg * 8;

  uint4 a0 = *(const uint4*)Ap0;
  uint4 a1 = *(const uint4*)Ap1;
  uint4 b0 = *(const uint4*)Bp0;
  uint4 b1 = *(const uint4*)Bp1;

  const int kg = lane >> 4;
  const int rsw = kg * 2;
  const int fr = lane & 15;

  for (int k0 = 0; k0 < Ksz; k0 += 32) {
    __syncthreads();
    *(uint4*)&As[skg][srow ^ wsw][0] = a0;
    *(uint4*)&As[skg][(srow + 64) ^ wsw][0] = a1;
    *(uint4*)&Bs[skg][srow ^ wsw][0] = b0;
    *(uint4*)&Bs[skg][(srow + 64) ^ wsw][0] = b1;
    __syncthreads();
    if (k0 + 32 < Ksz) {
      a0 = *(const uint4*)(Ap0 + k0 + 32);
      a1 = *(const uint4*)(Ap1 + k0 + 32);
      b0 = *(const uint4*)(Bp0 + k0 + 32);
      b1 = *(const uint4*)(Bp1 + k0 + 32);
    }
    bf16x8 af[4], bfv[4];
#pragma unroll
    for (int m = 0; m < 4; m++)
      af[m] = *(const bf16x8*)&As[kg][(wr * 64 + m * 16 + fr) ^ rsw][0];
#pragma unroll
    for (int n = 0; n < 4; n++)
      bfv[n] = *(const bf16x8*)&Bs[kg][(wc * 64 + n * 16 + fr) ^ rsw][0];
#pragma unroll
    for (int m = 0; m < 4; m++) {
#pragma unroll
      for (int n = 0; n < 4; n++) {
        acc[m][n] = __builtin_amdgcn_mfma_f32_16x16x32_bf16(af[m], bfv[n], acc[m][n], 0, 0, 0);
      }
    }
  }

  const int r4 = (lane >> 4) * 4;
#pragma unroll
  for (int m = 0; m < 4; m++) {
#pragma unroll
    for (int n = 0; n < 4; n++) {
      const int col = bcol + wc * 64 + n * 16 + fr;
      if constexpr (EPI == 4) {
        const int row0 = brow + wr * 64 + m * 16 + r4;
        ushort4 pk;
        pk.x = f2bf(acc[m][n][0]); pk.y = f2bf(acc[m][n][1]);
        pk.z = f2bf(acc[m][n][2]); pk.w = f2bf(acc[m][n][3]);
        *(ushort4*)((ushort*)Cout + (size_t)col * Msz + row0) = pk;
      } else {
#pragma unroll
        for (int r = 0; r < 4; r++) {
          const int row = brow + wr * 64 + m * 16 + r4 + r;
          float val = acc[m][n][r];
          size_t o = (size_t)row * Nsz + col;
          if constexpr (EPI == 0) ((ushort*)Cout)[o] = f2bf(val);
          else if constexpr (EPI == 1) ((float*)Cout)[o] = val;
          else if constexpr (EPI == 2) ((ushort*)Cout)[o] = f2bf(gelu_tanh(val + bias[col]));
          else ((float*)Cout)[o] = val + bias[col];
        }
      }
    }
  }
}

// ---------------- banded attention, MFMA flash-style ----------------
// Block: 32 queries (2 waves x 16) for one head. Keys for query ql (block-rel):
// s in [ql, ql+512], j = jb + s, R row r = 512 + ql - s in [0,512].
__global__ __launch_bounds__(128)
void attn_mfma(const ushort* __restrict__ qb, const ushort* __restrict__ kb,
               const ushort* __restrict__ Vt, const ushort* __restrict__ Rb,
               const float* __restrict__ ubias, const float* __restrict__ vbias,
               ushort* __restrict__ attb) {
  const int h = blockIdx.y;
  const int i0 = blockIdx.x * 32;
  const int tid = threadIdx.x;
  const int wave = tid >> 6, lane = tid & 63;
  const int g = lane >> 4, fr = lane & 15;

  __shared__ __align__(16) ushort BDall[2][16][536];
  __shared__ __align__(16) ushort Pl[2][16][40];

  // ---- Q fragments: (q+u) for AC, (q+v) for BD. A-row = fr, k = kst*32+g*8+j
  const int qi = i0 + wave * 16 + fr;
  bf16x8 afu[2], afv[2];
#pragma unroll
  for (int kst = 0; kst < 2; kst++) {
    const int dof = kst * 32 + g * 8;
    bf16x8 qv = *(const bf16x8*)(qb + (size_t)qi * D_ + h * DH_ + dof);
    const float* up = ubias + h * DH_ + dof;
    const float* vp = vbias + h * DH_ + dof;
    bf16x8 au, av;
#pragma unroll
    for (int j = 0; j < 8; j++) {
      float q = bf2f((ushort)qv[j]);
      au[j] = (short)f2bf(q + up[j]);
      av[j] = (short)f2bf(q + vp[j]);
    }
    afu[kst] = au; afv[kst] = av;
  }

  // ---- prologue: BDall[ql][r] = (q+v) . R[r], r in [0,527] (rows >512 never read)
#pragma unroll 1
  for (int t = 0; t < 33; t++) {
    const int r0 = t * 16;
    f32x4 acc = {};
#pragma unroll
    for (int kst = 0; kst < 2; kst++) {
      bf16x8 rf = *(const bf16x8*)(Rb + (size_t)(r0 + fr) * D_ + h * DH_ + kst * 32 + g * 8);
      acc = __builtin_amdgcn_mfma_f32_16x16x32_bf16(afv[kst], rf, acc, 0, 0, 0);
    }
#pragma unroll
    for (int rr = 0; rr < 4; rr++)
      BDall[wave][g * 4 + rr][r0 + fr] = f2bf(acc[rr]);
  }

  // ---- main loop: 17 chunks of 32 keys, flash online softmax
  const int jb = 256 + i0;
  const int smax = 2303 - i0;   // j <= L-1  <=>  s <= smax (block-relative)
  const int sbase = wave * 16;

  float m4[4], l4[4];
  f32x4 oacc[4] = {};
#pragma unroll
  for (int rr = 0; rr < 4; rr++) { m4[rr] = -1e30f; l4[rr] = 0.f; }

  for (int ch = 0; ch < 17; ch++) {
    const int c0 = sbase + ch * 32;
    f32x4 sc[2];
#pragma unroll
    for (int half = 0; half < 2; half++) {
      const int scol = c0 + half * 16 + fr;
      const int jc = (jb + scol < L_ - 1) ? (jb + scol) : (L_ - 1);
      f32x4 acc = {};
#pragma unroll
      for (int kst = 0; kst < 2; kst++) {
        bf16x8 kf = *(const bf16x8*)(kb + (size_t)jc * D_ + h * DH_ + kst * 32 + g * 8);
        acc = __builtin_amdgcn_mfma_f32_16x16x32_bf16(afu[kst], kf, acc, 0, 0, 0);
      }
      const int rbase = 512 + g * 4 - (ch * 32 + half * 16 + fr);
#pragma unroll
      for (int rr = 0; rr < 4; rr++) {
        const int r = rbase + rr;
        const int rcl = r < 0 ? 0 : (r > 512 ? 512 : r);
        const float bd = bf2f(BDall[wave][g * 4 + rr][rcl]);
        const bool valid = (r >= 0) && (r <= 512) && (scol <= smax);
        sc[half][rr] = valid ? (acc[rr] + bd) * 0.125f : -1e30f;
      }
    }
    // chunk row-max over the 16-lane group
    f32x4 cm;
#pragma unroll
    for (int rr = 0; rr < 4; rr++) cm[rr] = fmaxf(sc[0][rr], sc[1][rr]);
#pragma unroll
    for (int off = 8; off; off >>= 1)
#pragma unroll
      for (int rr = 0; rr < 4; rr++) cm[rr] = fmaxf(cm[rr], __shfl_xor(cm[rr], off));

    f32x4 pA, pB, rs;
#pragma unroll
    for (int rr = 0; rr < 4; rr++) {
      const float nm = fmaxf(m4[rr], cm[rr]);
      const float esc = __expf(m4[rr] - nm);
      m4[rr] = nm;
      pA[rr] = __expf(sc[0][rr] - nm);
      pB[rr] = __expf(sc[1][rr] - nm);
      rs[rr] = pA[rr] + pB[rr];
      l4[rr] *= esc;
#pragma unroll
      for (int n = 0; n < 4; n++) oacc[n][rr] *= esc;
    }
#pragma unroll
    for (int off = 8; off; off >>= 1)
#pragma unroll
      for (int rr = 0; rr < 4; rr++) rs[rr] += __shfl_xor(rs[rr], off);
#pragma unroll
    for (int rr = 0; rr < 4; rr++) l4[rr] += rs[rr];

    // P tile -> LDS (row = score row, col = key slot in chunk)
#pragma unroll
    for (int rr = 0; rr < 4; rr++) {
      Pl[wave][g * 4 + rr][fr]      = f2bf(pA[rr]);
      Pl[wave][g * 4 + rr][16 + fr] = f2bf(pB[rr]);
    }
    // PV: A = P (row=fr, k=g*8+j), B = Vt rows (dh cols), k = key
    bf16x8 pf = *(const bf16x8*)&Pl[wave][fr][g * 8];
    int kc = jb + c0 + g * 8;
    if (kc > L_ - 8) kc = L_ - 8;
#pragma unroll
    for (int n = 0; n < 4; n++) {
      bf16x8 vf = *(const bf16x8*)(Vt + (size_t)(h * DH_ + n * 16 + fr) * L_ + kc);
      oacc[n] = __builtin_amdgcn_mfma_f32_16x16x32_bf16(pf, vf, oacc[n], 0, 0, 0);
    }
  }

  // ---- epilogue
#pragma unroll
  for (int rr = 0; rr < 4; rr++) {
    const float inv = 1.f / l4[rr];
    const size_t rowo = (size_t)(i0 + sbase + g * 4 + rr) * D_ + h * DH_;
#pragma unroll
    for (int n = 0; n < 4; n++)
      attb[rowo + n * 16 + fr] = f2bf(oacc[n][rr] * inv);
  }
}

// ---------------- residual + LayerNorm ----------------
__global__ __launch_bounds__(256)
void ln_kernel(const float* __restrict__ a, const float* __restrict__ b,
               const float* __restrict__ gamma, const float* __restrict__ beta,
               float* __restrict__ outf, ushort* __restrict__ outb) {
  const int row = blockIdx.x;
  const int tid = threadIdx.x;
  const int wave = tid >> 6, lane = tid & 63;
  float4 va = ((const float4*)(a + (size_t)row * D_))[tid];
  float4 vb4 = ((const float4*)(b + (size_t)row * D_))[tid];
  float4 xv;
  xv.x = va.x + vb4.x; xv.y = va.y + vb4.y; xv.z = va.z + vb4.z; xv.w = va.w + vb4.w;
  float s = xv.x + xv.y + xv.z + xv.w;
  float q = xv.x * xv.x + xv.y * xv.y + xv.z * xv.z + xv.w * xv.w;
#pragma unroll
  for (int off = 32; off; off >>= 1) { s += __shfl_xor(s, off); q += __shfl_xor(q, off); }
  __shared__ float red[8];
  if (lane == 0) { red[wave * 2] = s; red[wave * 2 + 1] = q; }
  __syncthreads();
  float ts = red[0] + red[2] + red[4] + red[6];
  float tq = red[1] + red[3] + red[5] + red[7];
  float mu = ts * (1.f / D_);
  float var = tq * (1.f / D_) - mu * mu;
  float rs = rsqrtf(var + 1e-5f);
  float4 g4 = ((const float4*)gamma)[tid];
  float4 be4 = ((const float4*)beta)[tid];
  float4 y;
  y.x = (xv.x - mu) * rs * g4.x + be4.x;
  y.y = (xv.y - mu) * rs * g4.y + be4.y;
  y.z = (xv.z - mu) * rs * g4.z + be4.z;
  y.w = (xv.w - mu) * rs * g4.w + be4.w;
  ((float4*)(outf + (size_t)row * D_))[tid] = y;
  if (outb) ((ushort4*)(outb + (size_t)row * D_))[tid] = pack4(y);
}

extern "C" void kernel_launch(void* const* d_in, const int* in_sizes, int n_in,
                              void* d_out, int out_size, void* d_ws, size_t ws_size,
                              hipStream_t stream) {
  const float* x    = (const float*)d_in[0];
  const float* mem  = (const float*)d_in[1];
  const float* Wq   = (const float*)d_in[2];
  const float* Wk   = (const float*)d_in[3];
  const float* Wv   = (const float*)d_in[4];
  const float* Wo   = (const float*)d_in[5];
  const float* Wr   = (const float*)d_in[6];
  const float* u    = (const float*)d_in[7];
  const float* v    = (const float*)d_in[8];
  const float* ln1g = (const float*)d_in[9];
  const float* ln1b = (const float*)d_in[10];
  const float* W1   = (const float*)d_in[11];
  const float* b1   = (const float*)d_in[12];
  const float* W2   = (const float*)d_in[13];
  const float* b2   = (const float*)d_in[14];
  const float* ln2g = (const float*)d_in[15];
  const float* ln2b = (const float*)d_in[16];
  float* out = (float*)d_out;

  char* ws = (char*)d_ws;
  size_t off = 0;
  auto take = [&](size_t n) { char* p = ws + off; off += (n + 255) & ~(size_t)255; return p; };

  ushort* WqT = (ushort*)take(2097152);
  ushort* WkT = (ushort*)take(2097152);
  ushort* WvT = (ushort*)take(2097152);
  ushort* WoT = (ushort*)take(2097152);
  ushort* WrT = (ushort*)take(2097152);
  ushort* W1T = (ushort*)take(8388608);   // [4096][1024]
  ushort* W2T = (ushort*)take(8388608);   // [1024][4096]

  char* regA = take(10747904);            // xb + kvb + remb; later reused for f
  ushort* xb   = (ushort*)regA;                       // 4,194,304 B
  ushort* kvb  = (ushort*)(regA + 4194304);           // 5,242,880 B
  ushort* remb = (ushort*)(regA + 4194304 + 5242880); // 1,310,720 B
  float*  fbuf = (float*)regA;                        // 8,388,608 B (overlay)

  char* regB = take(20185088);            // qb,kb,Vt,Rb,attb; later reused for g
  ushort* qb   = (ushort*)regB;
  ushort* kb   = (ushort*)(regB + 4194304);
  ushort* Vt   = (ushort*)(regB + 9437184);           // [1024][2560] transposed V
  ushort* Rb   = (ushort*)(regB + 14680064);
  ushort* attb = (ushort*)(regB + 15990784);
  ushort* g    = (ushort*)regB;                       // 16,777,216 B (overlay)

  float*  o2 = (float*)take(8388608);
  float*  h  = (float*)take(8388608);
  ushort* hb = (ushort*)take(4194304);

  dim3 tb(32, 8);
  transpose_f32_to_bf16<<<dim3(32, 32), tb, 0, stream>>>(Wq, WqT, 1024, 1024);
  transpose_f32_to_bf16<<<dim3(32, 32), tb, 0, stream>>>(Wk, WkT, 1024, 1024);
  transpose_f32_to_bf16<<<dim3(32, 32), tb, 0, stream>>>(Wv, WvT, 1024, 1024);
  transpose_f32_to_bf16<<<dim3(32, 32), tb, 0, stream>>>(Wo, WoT, 1024, 1024);
  transpose_f32_to_bf16<<<dim3(32, 32), tb, 0, stream>>>(Wr, WrT, 1024, 1024);
  transpose_f32_to_bf16<<<dim3(128, 32), tb, 0, stream>>>(W1, W1T, 1024, 4096);
  transpose_f32_to_bf16<<<dim3(32, 128), tb, 0, stream>>>(W2, W2T, 4096, 1024);

  cvt_x_kv<<<4608, 256, 0, stream>>>(x, mem, xb, kvb);
  sinusoid_kernel<<<1280, 256, 0, stream>>>(remb);

  gemm_bt<0><<<dim3(8, 16), 256, 0, stream>>>(xb,   WqT, qb, nullptr, 2048, 1024, 1024);
  gemm_bt<0><<<dim3(8, 20), 256, 0, stream>>>(kvb,  WkT, kb, nullptr, 2560, 1024, 1024);
  gemm_bt<4><<<dim3(8, 20), 256, 0, stream>>>(kvb,  WvT, Vt, nullptr, 2560, 1024, 1024);
  gemm_bt<0><<<dim3(8, 5),  256, 0, stream>>>(remb, WrT, Rb, nullptr, 640, 1024, 1024);

  attn_mfma<<<dim3(64, 16), 128, 0, stream>>>(qb, kb, Vt, Rb, u, v, attb);

  gemm_bt<1><<<dim3(8, 16), 256, 0, stream>>>(attb, WoT, o2, nullptr, 2048, 1024, 1024);
  ln_kernel<<<2048, 256, 0, stream>>>(x, o2, ln1g, ln1b, h, hb);
  gemm_bt<2><<<dim3(32, 16), 256, 0, stream>>>(hb, W1T, g, b1, 2048, 4096, 1024);
  gemm_bt<3><<<dim3(8, 16), 256, 0, stream>>>(g, W2T, fbuf, b2, 2048, 1024, 4096);
  ln_kernel<<<2048, 256, 0, stream>>>(h, fbuf, ln2g, ln2b, out, nullptr);
}